// Round 13
// baseline (735.401 us; speedup 1.0000x reference)
//
#include <hip/hip_runtime.h>
#include <math.h>

#define E_EDGES 200000
#define N_NODES 10000
#define FDIM    128

typedef __attribute__((ext_vector_type(8))) short  short8;
typedef __attribute__((ext_vector_type(4))) float  float4v;

// ws layout: bf16 weights (ushort units), then sort scratch (byte offsets).
#define WT1_OFF   0            // Wt1[128][256]
#define WTW1_OFF  32768        // Wtw1[128][128]
#define WT2_OFF   49152        // Wt2[640][128]
#define WTW2_OFF  131072       // Wtw2[640][128]
#define W_TOTAL   212992       // ushorts = 425,984 bytes
#define CNT_BYTE  425984       // counts[10000] int
#define CUR_BYTE  465984       // cursor[10000] int
#define PERM_BYTE 505984       // perm[200000] int  (ends at 1,305,984 B)

#define EQ_OUT_SZ   (N_NODES * FDIM * 3)   // 3,840,000
#define INV_OUT_SZ  (N_NODES * FDIM)       // 1,280,000

__device__ __forceinline__ unsigned short f2bf(float x) {
    union { float f; unsigned u; } v; v.f = x;
    unsigned r = v.u + 0x7fffu + ((v.u >> 16) & 1u);
    return (unsigned short)(r >> 16);
}
__device__ __forceinline__ float bf2f(unsigned short h) {
    union { unsigned u; float f; } v; v.u = ((unsigned)h) << 16; return v.f;
}

// LDS-only barrier (R11: kept — traffic-neutral, +3%). lgkmcnt-only wait;
// global ops stay in flight across the barrier.
__device__ __forceinline__ void lds_barrier() {
    asm volatile("s_waitcnt lgkmcnt(0)" ::: "memory");
    __builtin_amdgcn_sched_barrier(0);
    __builtin_amdgcn_s_barrier();
    __builtin_amdgcn_sched_barrier(0);
}

// async global->LDS copy, 4B per lane: lane l loads g[l's addr] -> lds base
// + l*4. Global source is per-lane (can be permuted); LDS dest wave-uniform
// linear (rule #21).
__device__ __forceinline__ void async_se4(const float* g, float* l) {
    __builtin_amdgcn_global_load_lds(
        (const __attribute__((address_space(1))) unsigned int*)g,
        (__attribute__((address_space(3))) unsigned int*)l,
        4, 0, 0);
}

// PH2 swizzled-SoA word index (R13): plane c of row holds feature fl at
// word ((fl + c*16)&63) ^ k, k = ((row>>2)&3)<<4.
//  - k uses row bits 2-3: the 4 quad-rows {r,4+r,8+r,12+r} get distinct k
//    -> epilogue lanes sharing fl land on 2 distinct banks (2-way = free).
//  - c*16 rotation de-aliases the c-planes (c*64 = 0 mod 32) -> reduction's
//    4 red_c lanes sharing red_f also 2-way.
// gload_lds stays LDS-linear; the permutation is applied to the global
// SOURCE address (involution: fl(ln) = ((ln^k) - c*16)&63).
__device__ __forceinline__ int ph2_word(int row, int c, int fl) {
    const int k = ((row >> 2) & 3) << 4;
    return row * 256 + c * 64 + (((fl + c * 16) & 63) ^ k);
}

// XOR-swizzled tile accessor (16B-slot swizzle keyed on row&7).
__device__ __forceinline__ unsigned short* tile_ptr(unsigned short* base, int row, int col) {
    unsigned off = (unsigned)(row * 256 + col * 2);   // [32][128] ushort tile
    off ^= (unsigned)((row & 7) << 4);
    return (unsigned short*)((char*)base + off);
}

// ---------------- fused prologue: counts=0, weight transpose, out init ----
__global__ void prep_fused(const float* __restrict__ phiW1,
                           const float* __restrict__ wW1,
                           const float* __restrict__ phiW2,
                           const float* __restrict__ wW2,
                           unsigned short* __restrict__ ws,
                           int* __restrict__ counts,
                           const float* __restrict__ eq,
                           const float* __restrict__ inv,
                           float* __restrict__ out) {
    int t = blockIdx.x * 256 + threadIdx.x;
    if (t < N_NODES) counts[t] = 0;
    if (t < W_TOTAL) {
        if (t < 32768) {
            int n = t >> 8, k = t & 255;
            ws[WT1_OFF + t] = f2bf(phiW1[k * 128 + n]);
        } else if (t < 49152) {
            int i = t - 32768; int n = i >> 7, k = i & 127;
            ws[WTW1_OFF + i] = f2bf(wW1[k * 128 + n]);
        } else if (t < 131072) {
            int i = t - 49152; int n = i >> 7, k = i & 127;
            ws[WT2_OFF + i] = f2bf(phiW2[k * 640 + n]);
        } else {
            int i = t - 131072; int n = i >> 7, k = i & 127;
            ws[WTW2_OFF + i] = f2bf(wW2[k * 640 + n]);
        }
    }
    if (t < EQ_OUT_SZ / 4) {
        ((float4v*)out)[t] = ((const float4v*)eq)[t];
    } else {
        int u = t - EQ_OUT_SZ / 4;
        ((float4v*)(out + EQ_OUT_SZ))[u] = ((const float4v*)inv)[u];
    }
}

// ---------------- counting sort by dst ----------------
__global__ void hist_kernel(const int* __restrict__ eidx, int* __restrict__ counts) {
    int e = blockIdx.x * 256 + threadIdx.x;
    if (e < E_EDGES) atomicAdd(&counts[eidx[E_EDGES + e]], 1);
}
// R13: shfl-based scan — 2 barriers instead of 20 (this kernel runs on a
// single CU while 255 idle; barrier count is its critical path).
__global__ __launch_bounds__(1024)
void scan_kernel(const int* __restrict__ counts, int* __restrict__ cursor) {
    __shared__ int wsum[16];
    const int t = threadIdx.x;
    const int lane = t & 63;
    const int w = t >> 6;
    const int base = t * 10;                 // 1024*10 >= 10000
    int local[10];
    int s = 0;
    #pragma unroll
    for (int j = 0; j < 10; ++j) {
        int b = base + j;
        int v = (b < N_NODES) ? counts[b] : 0;
        local[j] = s; s += v;
    }
    // inclusive wave scan of s
    int ps = s;
    #pragma unroll
    for (int off = 1; off < 64; off <<= 1) {
        int n = __shfl_up(ps, off);
        if (lane >= off) ps += n;
    }
    if (lane == 63) wsum[w] = ps;
    __syncthreads();
    if (t < 16) {
        int x = wsum[t];
        #pragma unroll
        for (int off = 1; off < 16; off <<= 1) {
            int n = __shfl_up(x, off);
            if (t >= off) x += n;
        }
        wsum[t] = x;
    }
    __syncthreads();
    const int pre = ((w > 0) ? wsum[w - 1] : 0) + (ps - s);
    #pragma unroll
    for (int j = 0; j < 10; ++j) {
        int b = base + j;
        if (b < N_NODES) cursor[b] = pre + local[j];
    }
}
__global__ void scatter_kernel(const int* __restrict__ eidx,
                               int* __restrict__ cursor, int* __restrict__ perm) {
    int e = blockIdx.x * 256 + threadIdx.x;
    if (e < E_EDGES) {
        int d = eidx[E_EDGES + e];
        int pos = atomicAdd(&cursor[d], 1);
        perm[pos] = e;
    }
}

// ---------------- fused edge kernel: 32 sorted edges / block ----------------
// R12 structure + ONE delta: PH2 swizzled-SoA layout (ph2_word) kills the
// 4-way quad/plane bank conflicts the linear layout introduced (14.4M
// conflict-cycles -> ~5-6M expected).
__global__ __launch_bounds__(256, 3)
void edge_kernel(const int*   __restrict__ eidx,
                 const float* __restrict__ node_inv,
                 const float* __restrict__ eqf,
                 const float* __restrict__ edge_inv,
                 const float* __restrict__ dist,
                 const float* __restrict__ dir,
                 const float* __restrict__ phi_b1,
                 const float* __restrict__ phi_b2,
                 const float* __restrict__ w_b1,
                 const float* __restrict__ w_b2,
                 const unsigned short* __restrict__ wsW,
                 const int* __restrict__ perm,
                 float* __restrict__ out) {
    __shared__ __align__(16) unsigned char smem_u[32768];
    __shared__ int   s_e[32], s_src[32], s_dst[32];
    __shared__ float s_dir[32][3];
    __shared__ float s_dist[32];

    unsigned short* A1a = (unsigned short*)smem_u;              // [32][128] swz
    unsigned short* A1b = (unsigned short*)(smem_u + 8192);     // [32][128] swz
    unsigned short* H1  = (unsigned short*)(smem_u + 16384);    // [32][128] swz
    unsigned short* H2  = (unsigned short*)(smem_u + 24576);    // [32][128] swz
    // phase 2: PH2[32][256] f32 = 32KB, swizzled SoA via ph2_word.
    float* PH2 = (float*)smem_u;

    const int tid = threadIdx.x;
    const int p0  = blockIdx.x * 32;

    if (tid < 32) {
        int e = perm[p0 + tid];
        s_e[tid]   = e;
        s_src[tid] = eidx[e];
        s_dst[tid] = eidx[E_EDGES + e];
        s_dir[tid][0] = dir[e * 3 + 0];
        s_dir[tid][1] = dir[e * 3 + 1];
        s_dir[tid][2] = dir[e * 3 + 2];
        s_dist[tid]  = dist[e];
    }
    lds_barrier();

    // ---- stage A1a (node_inv[src]) and A1b (edge_inv[e]) as bf16 ----
    {
        const int i   = tid >> 3;        // row 0..31
        const int seg = tid & 7;         // 0..7
        const int k0  = seg * 32;
        const float* base;
        unsigned short* tb;
        int c0;
        if (k0 < 128) { base = node_inv + (size_t)s_src[i] * 128 + k0; tb = A1a; c0 = k0; }
        else          { base = edge_inv + (size_t)s_e[i]  * 128 + (k0 - 128); tb = A1b; c0 = k0 - 128; }
        #pragma unroll
        for (int j = 0; j < 4; ++j) {
            float4v v0 = *(const float4v*)(base + j * 8);
            float4v v1 = *(const float4v*)(base + j * 8 + 4);
            short8 sv;
            #pragma unroll
            for (int u = 0; u < 4; ++u) {
                sv[u]     = (short)f2bf(v0[u]);
                sv[u + 4] = (short)f2bf(v1[u]);
            }
            *(short8*)tile_ptr(tb, i, c0 + j * 8) = sv;
        }
    }
    lds_barrier();

    const int wv   = tid >> 6;
    const int ln   = tid & 63;
    const int l16  = ln & 15;
    const int quad = ln >> 4;

    const unsigned short* Wt1  = wsW + WT1_OFF;
    const unsigned short* Wtw1 = wsW + WTW1_OFF;
    const unsigned short* Wt2  = wsW + WT2_OFF;
    const unsigned short* Wtw2 = wsW + WTW2_OFF;

    const float4v zero4 = {0.f, 0.f, 0.f, 0.f};

    // ---- phase 1: H1 = silu(A1 @ phiW1 + b1), H2 = silu(PE @ wW1 + wb1) ----
    float4v acc1[2][2], acc2[2][2];
    #pragma unroll
    for (int rt = 0; rt < 2; ++rt)
        #pragma unroll
        for (int ct = 0; ct < 2; ++ct) { acc1[rt][ct] = zero4; acc2[rt][ct] = zero4; }

    #pragma unroll
    for (int kk = 0; kk < 4; ++kk) {        // K 0..127 (node part)
        const int k = kk * 32 + quad * 8;
        short8 a0 = *(const short8*)tile_ptr(A1a, l16, k);
        short8 a1 = *(const short8*)tile_ptr(A1a, 16 + l16, k);
        #pragma unroll
        for (int ct = 0; ct < 2; ++ct) {
            const int n = wv * 32 + ct * 16 + l16;
            short8 b = *(const short8*)&Wt1[n * 256 + k];
            acc1[0][ct] = __builtin_amdgcn_mfma_f32_16x16x32_bf16(a0, b, acc1[0][ct], 0, 0, 0);
            acc1[1][ct] = __builtin_amdgcn_mfma_f32_16x16x32_bf16(a1, b, acc1[1][ct], 0, 0, 0);
        }
    }
    #pragma unroll
    for (int kk = 0; kk < 4; ++kk) {        // K 128..255 (edge part)
        const int k = kk * 32 + quad * 8;
        short8 a0 = *(const short8*)tile_ptr(A1b, l16, k);
        short8 a1 = *(const short8*)tile_ptr(A1b, 16 + l16, k);
        #pragma unroll
        for (int ct = 0; ct < 2; ++ct) {
            const int n = wv * 32 + ct * 16 + l16;
            short8 b = *(const short8*)&Wt1[n * 256 + 128 + k];
            acc1[0][ct] = __builtin_amdgcn_mfma_f32_16x16x32_bf16(a0, b, acc1[0][ct], 0, 0, 0);
            acc1[1][ct] = __builtin_amdgcn_mfma_f32_16x16x32_bf16(a1, b, acc1[1][ct], 0, 0, 0);
        }
    }
    // PE fragments in registers: rows l16 and 16+l16, k = quad*8.
    {
        const float cst = 3.14159265358979323846f / 10.0f;
        const float d0 = s_dist[l16] * cst;
        const float d1 = s_dist[16 + l16] * cst;
        short8 pe0[4], pe1[4];
        #pragma unroll
        for (int kk = 0; kk < 4; ++kk) {
            short8 s0, s1;
            #pragma unroll
            for (int u = 0; u < 8; ++u) {
                const int f = kk * 32 + quad * 8 + u;
                const float fa = (float)((kk < 2) ? f : (f - 64));
                float v0, v1;
                if (kk < 2) { v0 = __sinf(d0 * fa); v1 = __sinf(d1 * fa); }
                else        { v0 = __cosf(d0 * fa); v1 = __cosf(d1 * fa); }
                s0[u] = (short)f2bf(v0);
                s1[u] = (short)f2bf(v1);
            }
            pe0[kk] = s0; pe1[kk] = s1;
        }
        #pragma unroll
        for (int kk = 0; kk < 4; ++kk) {    // PE GEMM, K = 128
            const int k = kk * 32 + quad * 8;
            #pragma unroll
            for (int ct = 0; ct < 2; ++ct) {
                const int n = wv * 32 + ct * 16 + l16;
                short8 b = *(const short8*)&Wtw1[n * 128 + k];
                acc2[0][ct] = __builtin_amdgcn_mfma_f32_16x16x32_bf16(pe0[kk], b, acc2[0][ct], 0, 0, 0);
                acc2[1][ct] = __builtin_amdgcn_mfma_f32_16x16x32_bf16(pe1[kk], b, acc2[1][ct], 0, 0, 0);
            }
        }
    }
    // silu + store H (C/D: col = l16, row = quad*4 + reg)
    #pragma unroll
    for (int ct = 0; ct < 2; ++ct) {
        const int n = wv * 32 + ct * 16 + l16;
        const float b1v  = phi_b1[n];
        const float bw1v = w_b1[n];
        #pragma unroll
        for (int rt = 0; rt < 2; ++rt)
            #pragma unroll
            for (int r = 0; r < 4; ++r) {
                const int row = rt * 16 + quad * 4 + r;
                float x = acc1[rt][ct][r] + b1v;
                *tile_ptr(H1, row, n) = f2bf(x / (1.f + __expf(-x)));
                float y = acc2[rt][ct][r] + bw1v;
                *tile_ptr(H2, row, n) = f2bf(y / (1.f + __expf(-y)));
            }
    }
    lds_barrier();        // H ready

    // ---- phase 2: 2 chunks of 64 features ----
    float* eq_out   = out;
    float* inv_out  = out + EQ_OUT_SZ;
    float* edge_out = out + EQ_OUT_SZ + INV_OUT_SZ;

    // hoist A-fragments + a1bv; after this, the tile region is dead -> PH2.
    short8 ha[2][4], hb[2][4];
    #pragma unroll
    for (int rt = 0; rt < 2; ++rt)
        #pragma unroll
        for (int kk = 0; kk < 4; ++kk) {
            const int k = kk * 32 + quad * 8;
            ha[rt][kk] = *(const short8*)tile_ptr(H1, rt * 16 + l16, k);
            hb[rt][kk] = *(const short8*)tile_ptr(H2, rt * 16 + l16, k);
        }
    unsigned short a1bv[2][8];
    #pragma unroll
    for (int fc2 = 0; fc2 < 2; ++fc2)
        #pragma unroll
        for (int rt = 0; rt < 2; ++rt)
            #pragma unroll
            for (int rr = 0; rr < 4; ++rr)
                a1bv[fc2][rt * 4 + rr] =
                    *tile_ptr(A1b, rt * 16 + quad * 4 + rr, fc2 * 64 + wv * 16 + l16);
    lds_barrier();        // everyone done reading tiles; PH2 region free

    const int red_f = tid >> 2;             // 0..63: feature within chunk
    const int red_c = tid & 3;              // 0..3 : component (xyz | ds)

    #pragma unroll
    for (int fc2 = 0; fc2 < 2; ++fc2) {
        // issue se prefetch: wave wv covers rows wv*8..wv*8+7; per row, 3
        // c-planes with PRE-SWIZZLED global source (LDS dest stays linear).
        {
            const int r0 = wv * 8;
            #pragma unroll
            for (int rr = 0; rr < 8; ++rr) {
                const int row = r0 + rr;
                const int k = ((row >> 2) & 3) << 4;
                float* l = PH2 + row * 256;
                const size_t gb = ((size_t)s_src[row] * 128 + fc2 * 64);
                #pragma unroll
                for (int c = 0; c < 3; ++c) {
                    const int fl = ((ln ^ k) - c * 16) & 63;
                    async_se4(eqf + (gb + fl) * 3 + c, l + c * 64);
                }
            }
        }
        // gate GEMMs (prefetch resolves underneath)
        float4v mv[2][5];
        #pragma unroll
        for (int g = 0; g < 5; ++g) {
            const int n = g * 128 + fc2 * 64 + wv * 16 + l16;
            float4v p1a = zero4, p1b = zero4, p2a = zero4, p2b = zero4;
            #pragma unroll
            for (int kk = 0; kk < 4; ++kk) {
                const int k = kk * 32 + quad * 8;
                short8 b1f = *(const short8*)&Wt2[n * 128 + k];
                short8 b2f = *(const short8*)&Wtw2[n * 128 + k];
                p1a = __builtin_amdgcn_mfma_f32_16x16x32_bf16(ha[0][kk], b1f, p1a, 0, 0, 0);
                p1b = __builtin_amdgcn_mfma_f32_16x16x32_bf16(ha[1][kk], b1f, p1b, 0, 0, 0);
                p2a = __builtin_amdgcn_mfma_f32_16x16x32_bf16(hb[0][kk], b2f, p2a, 0, 0, 0);
                p2b = __builtin_amdgcn_mfma_f32_16x16x32_bf16(hb[1][kk], b2f, p2b, 0, 0, 0);
            }
            const float b2v  = phi_b2[n];
            const float bw2v = w_b2[n];
            mv[0][g] = (p1a + b2v) * (p2a + bw2v);
            mv[1][g] = (p1b + b2v) * (p2b + bw2v);
        }
        // drain own prefetches, then sync so all waves' rows are visible.
        asm volatile("s_waitcnt vmcnt(0)" ::: "memory");
        __builtin_amdgcn_sched_barrier(0);
        lds_barrier();
        // epilogue: se from LDS (swizzled), dq direct; v overwrites in place
        {
            const int fl = wv * 16 + l16;        // 0..63 within chunk
            const int fg = fc2 * 64 + fl;
            #pragma unroll
            for (int rt = 0; rt < 2; ++rt) {
                #pragma unroll
                for (int r = 0; r < 4; ++r) {
                    const int row = rt * 16 + quad * 4 + r;
                    const float gate = mv[rt][0][r];
                    const float cpg  = mv[rt][1][r];
                    const float sc   = mv[rt][2][r];
                    const float dsv  = mv[rt][3][r];
                    const float dev  = mv[rt][4][r];
                    const int dn = s_dst[row], e = s_e[row];
                    const float ex = s_dir[row][0], ey = s_dir[row][1], ez = s_dir[row][2];
                    const float sx = PH2[ph2_word(row, 0, fl)];
                    const float sy = PH2[ph2_word(row, 1, fl)];
                    const float sz = PH2[ph2_word(row, 2, fl)];
                    const float* dq = eqf + ((size_t)dn * 128 + fg) * 3;
                    const float dx = dq[0], dy = dq[1], dz = dq[2];
                    const float cx = ey * dz - ez * dy;
                    const float cy = ez * dx - ex * dz;
                    const float cz = ex * dy - ey * dx;
                    PH2[ph2_word(row, 0, fl)] = sc * ex + gate * sx + cpg * cx;
                    PH2[ph2_word(row, 1, fl)] = sc * ey + gate * sy + cpg * cy;
                    PH2[ph2_word(row, 2, fl)] = sc * ez + gate * sz + cpg * cz;
                    PH2[ph2_word(row, 3, fl)] = dsv;
                    edge_out[(size_t)e * 128 + fg] = bf2f(a1bv[fc2][rt * 4 + r]) + dev;
                }
            }
        }
        lds_barrier();
        // segmented reduction over ALL 32 sorted-dst rows (~1 atomic per run)
        {
            const int fgr = fc2 * 64 + red_f;
            float acc = 0.f;
            int prev = s_dst[0];
            #pragma unroll
            for (int r = 0; r < 32; ++r) {
                const int d = s_dst[r];
                const float v = PH2[ph2_word(r, red_c, red_f)];
                if (d != prev) {
                    if (red_c < 3) atomicAdd(eq_out + ((size_t)prev * 128 + fgr) * 3 + red_c, acc);
                    else           atomicAdd(inv_out + (size_t)prev * 128 + fgr, acc);
                    acc = 0.f; prev = d;
                }
                acc += v;
            }
            if (red_c < 3) atomicAdd(eq_out + ((size_t)prev * 128 + fgr) * 3 + red_c, acc);
            else           atomicAdd(inv_out + (size_t)prev * 128 + fgr, acc);
        }
        lds_barrier();
    }
}

extern "C" void kernel_launch(void* const* d_in, const int* in_sizes, int n_in,
                              void* d_out, int out_size, void* d_ws, size_t ws_size,
                              hipStream_t stream) {
    const int*   eidx     = (const int*)d_in[0];
    const float* node_inv = (const float*)d_in[1];
    const float* eqf      = (const float*)d_in[2];
    const float* edge_inv = (const float*)d_in[3];
    const float* dist     = (const float*)d_in[4];
    const float* dir      = (const float*)d_in[5];
    const float* phi_W1   = (const float*)d_in[6];
    const float* phi_b1   = (const float*)d_in[7];
    const float* phi_W2   = (const float*)d_in[8];
    const float* phi_b2   = (const float*)d_in[9];
    const float* w_W1     = (const float*)d_in[10];
    const float* w_b1     = (const float*)d_in[11];
    const float* w_W2     = (const float*)d_in[12];
    const float* w_b2     = (const float*)d_in[13];
    float* out = (float*)d_out;
    unsigned short* wsW = (unsigned short*)d_ws;
    int* counts = (int*)((char*)d_ws + CNT_BYTE);
    int* cursor = (int*)((char*)d_ws + CUR_BYTE);
    int* perm   = (int*)((char*)d_ws + PERM_BYTE);

    prep_fused<<<(EQ_OUT_SZ + INV_OUT_SZ) / 4 / 256, 256, 0, stream>>>(
        phi_W1, w_W1, phi_W2, w_W2, wsW, counts, eqf, node_inv, out);
    hist_kernel<<<(E_EDGES + 255) / 256, 256, 0, stream>>>(eidx, counts);
    scan_kernel<<<1, 1024, 0, stream>>>(counts, cursor);
    scatter_kernel<<<(E_EDGES + 255) / 256, 256, 0, stream>>>(eidx, cursor, perm);
    edge_kernel<<<E_EDGES / 32, 256, 0, stream>>>(eidx, node_inv, eqf, edge_inv, dist, dir,
                                                  phi_b1, phi_b2, w_b1, w_b2, wsW, perm, out);
}

// Round 15
// 661.315 us; speedup vs baseline: 1.1120x; 1.1120x over previous
//
#include <hip/hip_runtime.h>
#include <math.h>

#define E_EDGES 200000
#define N_NODES 10000
#define FDIM    128

typedef __attribute__((ext_vector_type(8))) short  short8;
typedef __attribute__((ext_vector_type(4))) float  float4v;

// ws layout: bf16 weights (ushort units), then sort scratch (byte offsets).
#define WT1_OFF   0            // Wt1[128][256]
#define WTW1_OFF  32768        // Wtw1[128][128]
#define WT2_OFF   49152        // Wt2[640][128]
#define WTW2_OFF  131072       // Wtw2[640][128]
#define W_TOTAL   212992       // ushorts = 425,984 bytes
#define CNT_BYTE  425984       // counts[10000] int
#define CUR_BYTE  465984       // cursor[10000] int
#define PERM_BYTE 505984       // perm[200000] int  (ends at 1,305,984 B)

#define EQ_OUT_SZ   (N_NODES * FDIM * 3)   // 3,840,000
#define INV_OUT_SZ  (N_NODES * FDIM)       // 1,280,000

// PH2 row stride in f32 words. 260 (not 256): 260 mod 8 = 4, so the
// epilogue's quad-row distance 4*260 = 1040 = 16 mod 32 banks -> 2-way
// (free, m136) instead of the 4-way that 256 gave (R12: 14.4M conflicts).
// gload_lds only constrains the per-instruction dest (wave-uniform base +
// lane*4, 64 contiguous words); row stride is free.
#define PH2_STRIDE 260

__device__ __forceinline__ unsigned short f2bf(float x) {
    union { float f; unsigned u; } v; v.f = x;
    unsigned r = v.u + 0x7fffu + ((v.u >> 16) & 1u);
    return (unsigned short)(r >> 16);
}
__device__ __forceinline__ float bf2f(unsigned short h) {
    union { unsigned u; float f; } v; v.u = ((unsigned)h) << 16; return v.f;
}

// LDS-only barrier (R11: kept). lgkmcnt-only wait; global ops stay in
// flight across the barrier.
__device__ __forceinline__ void lds_barrier() {
    asm volatile("s_waitcnt lgkmcnt(0)" ::: "memory");
    __builtin_amdgcn_sched_barrier(0);
    __builtin_amdgcn_s_barrier();
    __builtin_amdgcn_sched_barrier(0);
}

// async global->LDS copy, 4B per lane: lane l loads g[+l*4] -> lds[+l*4].
// Source kept CONTIGUOUS (R13 lesson: source permutations that break
// per-instruction contiguity cost 3x line-fetches > any bank savings).
__device__ __forceinline__ void async_se4(const float* g, float* l) {
    __builtin_amdgcn_global_load_lds(
        (const __attribute__((address_space(1))) unsigned int*)g,
        (__attribute__((address_space(3))) unsigned int*)l,
        4, 0, 0);
}

// XOR-swizzled tile accessor (16B-slot swizzle keyed on row&7).
__device__ __forceinline__ unsigned short* tile_ptr(unsigned short* base, int row, int col) {
    unsigned off = (unsigned)(row * 256 + col * 2);   // [32][128] ushort tile
    off ^= (unsigned)((row & 7) << 4);
    return (unsigned short*)((char*)base + off);
}

// ---------------- fused prologue: counts=0, weight transpose, out init ----
__global__ void prep_fused(const float* __restrict__ phiW1,
                           const float* __restrict__ wW1,
                           const float* __restrict__ phiW2,
                           const float* __restrict__ wW2,
                           unsigned short* __restrict__ ws,
                           int* __restrict__ counts,
                           const float* __restrict__ eq,
                           const float* __restrict__ inv,
                           float* __restrict__ out) {
    int t = blockIdx.x * 256 + threadIdx.x;
    if (t < N_NODES) counts[t] = 0;
    if (t < W_TOTAL) {
        if (t < 32768) {
            int n = t >> 8, k = t & 255;
            ws[WT1_OFF + t] = f2bf(phiW1[k * 128 + n]);
        } else if (t < 49152) {
            int i = t - 32768; int n = i >> 7, k = i & 127;
            ws[WTW1_OFF + i] = f2bf(wW1[k * 128 + n]);
        } else if (t < 131072) {
            int i = t - 49152; int n = i >> 7, k = i & 127;
            ws[WT2_OFF + i] = f2bf(phiW2[k * 640 + n]);
        } else {
            int i = t - 131072; int n = i >> 7, k = i & 127;
            ws[WTW2_OFF + i] = f2bf(wW2[k * 640 + n]);
        }
    }
    if (t < EQ_OUT_SZ / 4) {
        ((float4v*)out)[t] = ((const float4v*)eq)[t];
    } else {
        int u = t - EQ_OUT_SZ / 4;
        ((float4v*)(out + EQ_OUT_SZ))[u] = ((const float4v*)inv)[u];
    }
}

// ---------------- counting sort by dst ----------------
__global__ void hist_kernel(const int* __restrict__ eidx, int* __restrict__ counts) {
    int e = blockIdx.x * 256 + threadIdx.x;
    if (e < E_EDGES) atomicAdd(&counts[eidx[E_EDGES + e]], 1);
}
// shfl-based scan (R13: kept) — 2 barriers instead of 20.
__global__ __launch_bounds__(1024)
void scan_kernel(const int* __restrict__ counts, int* __restrict__ cursor) {
    __shared__ int wsum[16];
    const int t = threadIdx.x;
    const int lane = t & 63;
    const int w = t >> 6;
    const int base = t * 10;                 // 1024*10 >= 10000
    int local[10];
    int s = 0;
    #pragma unroll
    for (int j = 0; j < 10; ++j) {
        int b = base + j;
        int v = (b < N_NODES) ? counts[b] : 0;
        local[j] = s; s += v;
    }
    // inclusive wave scan of s
    int ps = s;
    #pragma unroll
    for (int off = 1; off < 64; off <<= 1) {
        int n = __shfl_up(ps, off);
        if (lane >= off) ps += n;
    }
    if (lane == 63) wsum[w] = ps;
    __syncthreads();
    if (t < 16) {
        int x = wsum[t];
        #pragma unroll
        for (int off = 1; off < 16; off <<= 1) {
            int n = __shfl_up(x, off);
            if (t >= off) x += n;
        }
        wsum[t] = x;
    }
    __syncthreads();
    const int pre = ((w > 0) ? wsum[w - 1] : 0) + (ps - s);
    #pragma unroll
    for (int j = 0; j < 10; ++j) {
        int b = base + j;
        if (b < N_NODES) cursor[b] = pre + local[j];
    }
}
__global__ void scatter_kernel(const int* __restrict__ eidx,
                               int* __restrict__ cursor, int* __restrict__ perm) {
    int e = blockIdx.x * 256 + threadIdx.x;
    if (e < E_EDGES) {
        int d = eidx[E_EDGES + e];
        int pos = atomicAdd(&cursor[d], 1);
        perm[pos] = e;
    }
}

// ---------------- fused edge kernel: 32 sorted edges / block ----------------
// R12 structure (best verified: 483 us) + ONE delta: PH2 row stride 256->260
// (kills the 4-way epilogue quad conflict; source stays contiguous/coalesced).
__global__ __launch_bounds__(256, 3)
void edge_kernel(const int*   __restrict__ eidx,
                 const float* __restrict__ node_inv,
                 const float* __restrict__ eqf,
                 const float* __restrict__ edge_inv,
                 const float* __restrict__ dist,
                 const float* __restrict__ dir,
                 const float* __restrict__ phi_b1,
                 const float* __restrict__ phi_b2,
                 const float* __restrict__ w_b1,
                 const float* __restrict__ w_b2,
                 const unsigned short* __restrict__ wsW,
                 const int* __restrict__ perm,
                 float* __restrict__ out) {
    __shared__ __align__(16) unsigned char smem_u[PH2_STRIDE * 32 * 4];  // 33,280 B
    __shared__ int   s_e[32], s_src[32], s_dst[32];
    __shared__ float s_dir[32][3];
    __shared__ float s_dist[32];

    unsigned short* A1a = (unsigned short*)smem_u;              // [32][128] swz
    unsigned short* A1b = (unsigned short*)(smem_u + 8192);     // [32][128] swz
    unsigned short* H1  = (unsigned short*)(smem_u + 16384);    // [32][128] swz
    unsigned short* H2  = (unsigned short*)(smem_u + 24576);    // [32][128] swz
    // phase 2: PH2[32][PH2_STRIDE] f32, words 0..191 = AoS se/v, 192..255 = ds.
    float* PH2 = (float*)smem_u;

    const int tid = threadIdx.x;
    const int p0  = blockIdx.x * 32;

    if (tid < 32) {
        int e = perm[p0 + tid];
        s_e[tid]   = e;
        s_src[tid] = eidx[e];
        s_dst[tid] = eidx[E_EDGES + e];
        s_dir[tid][0] = dir[e * 3 + 0];
        s_dir[tid][1] = dir[e * 3 + 1];
        s_dir[tid][2] = dir[e * 3 + 2];
        s_dist[tid]  = dist[e];
    }
    lds_barrier();

    // ---- stage A1a (node_inv[src]) and A1b (edge_inv[e]) as bf16 ----
    {
        const int i   = tid >> 3;        // row 0..31
        const int seg = tid & 7;         // 0..7
        const int k0  = seg * 32;
        const float* base;
        unsigned short* tb;
        int c0;
        if (k0 < 128) { base = node_inv + (size_t)s_src[i] * 128 + k0; tb = A1a; c0 = k0; }
        else          { base = edge_inv + (size_t)s_e[i]  * 128 + (k0 - 128); tb = A1b; c0 = k0 - 128; }
        #pragma unroll
        for (int j = 0; j < 4; ++j) {
            float4v v0 = *(const float4v*)(base + j * 8);
            float4v v1 = *(const float4v*)(base + j * 8 + 4);
            short8 sv;
            #pragma unroll
            for (int u = 0; u < 4; ++u) {
                sv[u]     = (short)f2bf(v0[u]);
                sv[u + 4] = (short)f2bf(v1[u]);
            }
            *(short8*)tile_ptr(tb, i, c0 + j * 8) = sv;
        }
    }
    lds_barrier();

    const int wv   = tid >> 6;
    const int ln   = tid & 63;
    const int l16  = ln & 15;
    const int quad = ln >> 4;

    const unsigned short* Wt1  = wsW + WT1_OFF;
    const unsigned short* Wtw1 = wsW + WTW1_OFF;
    const unsigned short* Wt2  = wsW + WT2_OFF;
    const unsigned short* Wtw2 = wsW + WTW2_OFF;

    const float4v zero4 = {0.f, 0.f, 0.f, 0.f};

    // ---- phase 1: H1 = silu(A1 @ phiW1 + b1), H2 = silu(PE @ wW1 + wb1) ----
    float4v acc1[2][2], acc2[2][2];
    #pragma unroll
    for (int rt = 0; rt < 2; ++rt)
        #pragma unroll
        for (int ct = 0; ct < 2; ++ct) { acc1[rt][ct] = zero4; acc2[rt][ct] = zero4; }

    #pragma unroll
    for (int kk = 0; kk < 4; ++kk) {        // K 0..127 (node part)
        const int k = kk * 32 + quad * 8;
        short8 a0 = *(const short8*)tile_ptr(A1a, l16, k);
        short8 a1 = *(const short8*)tile_ptr(A1a, 16 + l16, k);
        #pragma unroll
        for (int ct = 0; ct < 2; ++ct) {
            const int n = wv * 32 + ct * 16 + l16;
            short8 b = *(const short8*)&Wt1[n * 256 + k];
            acc1[0][ct] = __builtin_amdgcn_mfma_f32_16x16x32_bf16(a0, b, acc1[0][ct], 0, 0, 0);
            acc1[1][ct] = __builtin_amdgcn_mfma_f32_16x16x32_bf16(a1, b, acc1[1][ct], 0, 0, 0);
        }
    }
    #pragma unroll
    for (int kk = 0; kk < 4; ++kk) {        // K 128..255 (edge part)
        const int k = kk * 32 + quad * 8;
        short8 a0 = *(const short8*)tile_ptr(A1b, l16, k);
        short8 a1 = *(const short8*)tile_ptr(A1b, 16 + l16, k);
        #pragma unroll
        for (int ct = 0; ct < 2; ++ct) {
            const int n = wv * 32 + ct * 16 + l16;
            short8 b = *(const short8*)&Wt1[n * 256 + 128 + k];
            acc1[0][ct] = __builtin_amdgcn_mfma_f32_16x16x32_bf16(a0, b, acc1[0][ct], 0, 0, 0);
            acc1[1][ct] = __builtin_amdgcn_mfma_f32_16x16x32_bf16(a1, b, acc1[1][ct], 0, 0, 0);
        }
    }
    // PE fragments in registers: rows l16 and 16+l16, k = quad*8.
    {
        const float cst = 3.14159265358979323846f / 10.0f;
        const float d0 = s_dist[l16] * cst;
        const float d1 = s_dist[16 + l16] * cst;
        short8 pe0[4], pe1[4];
        #pragma unroll
        for (int kk = 0; kk < 4; ++kk) {
            short8 s0, s1;
            #pragma unroll
            for (int u = 0; u < 8; ++u) {
                const int f = kk * 32 + quad * 8 + u;
                const float fa = (float)((kk < 2) ? f : (f - 64));
                float v0, v1;
                if (kk < 2) { v0 = __sinf(d0 * fa); v1 = __sinf(d1 * fa); }
                else        { v0 = __cosf(d0 * fa); v1 = __cosf(d1 * fa); }
                s0[u] = (short)f2bf(v0);
                s1[u] = (short)f2bf(v1);
            }
            pe0[kk] = s0; pe1[kk] = s1;
        }
        #pragma unroll
        for (int kk = 0; kk < 4; ++kk) {    // PE GEMM, K = 128
            const int k = kk * 32 + quad * 8;
            #pragma unroll
            for (int ct = 0; ct < 2; ++ct) {
                const int n = wv * 32 + ct * 16 + l16;
                short8 b = *(const short8*)&Wtw1[n * 128 + k];
                acc2[0][ct] = __builtin_amdgcn_mfma_f32_16x16x32_bf16(pe0[kk], b, acc2[0][ct], 0, 0, 0);
                acc2[1][ct] = __builtin_amdgcn_mfma_f32_16x16x32_bf16(pe1[kk], b, acc2[1][ct], 0, 0, 0);
            }
        }
    }
    // silu + store H (C/D: col = l16, row = quad*4 + reg)
    #pragma unroll
    for (int ct = 0; ct < 2; ++ct) {
        const int n = wv * 32 + ct * 16 + l16;
        const float b1v  = phi_b1[n];
        const float bw1v = w_b1[n];
        #pragma unroll
        for (int rt = 0; rt < 2; ++rt)
            #pragma unroll
            for (int r = 0; r < 4; ++r) {
                const int row = rt * 16 + quad * 4 + r;
                float x = acc1[rt][ct][r] + b1v;
                *tile_ptr(H1, row, n) = f2bf(x / (1.f + __expf(-x)));
                float y = acc2[rt][ct][r] + bw1v;
                *tile_ptr(H2, row, n) = f2bf(y / (1.f + __expf(-y)));
            }
    }
    lds_barrier();        // H ready

    // ---- phase 2: 2 chunks of 64 features ----
    float* eq_out   = out;
    float* inv_out  = out + EQ_OUT_SZ;
    float* edge_out = out + EQ_OUT_SZ + INV_OUT_SZ;

    // hoist A-fragments + a1bv; after this, the tile region is dead -> PH2.
    short8 ha[2][4], hb[2][4];
    #pragma unroll
    for (int rt = 0; rt < 2; ++rt)
        #pragma unroll
        for (int kk = 0; kk < 4; ++kk) {
            const int k = kk * 32 + quad * 8;
            ha[rt][kk] = *(const short8*)tile_ptr(H1, rt * 16 + l16, k);
            hb[rt][kk] = *(const short8*)tile_ptr(H2, rt * 16 + l16, k);
        }
    unsigned short a1bv[2][8];
    #pragma unroll
    for (int fc2 = 0; fc2 < 2; ++fc2)
        #pragma unroll
        for (int rt = 0; rt < 2; ++rt)
            #pragma unroll
            for (int rr = 0; rr < 4; ++rr)
                a1bv[fc2][rt * 4 + rr] =
                    *tile_ptr(A1b, rt * 16 + quad * 4 + rr, fc2 * 64 + wv * 16 + l16);
    lds_barrier();        // everyone done reading tiles; PH2 region free

    const int red_f = tid >> 2;             // 0..63: feature within chunk
    const int red_c = tid & 3;              // 0..3 : component (xyz | ds)
    const int red_fo = (red_c < 3) ? (red_f * 3 + red_c) : (192 + red_f);

    #pragma unroll
    for (int fc2 = 0; fc2 < 2; ++fc2) {
        // issue se prefetch: wave wv covers rows wv*8..wv*8+7, 3 contiguous
        // 64-word planes per row (fully coalesced source).
        {
            const int r0 = wv * 8;
            #pragma unroll
            for (int rr = 0; rr < 8; ++rr) {
                const int row = r0 + rr;
                const float* g = eqf + ((size_t)s_src[row] * 128 + fc2 * 64) * 3 + ln;
                float* l = PH2 + row * PH2_STRIDE;
                async_se4(g,       l);
                async_se4(g + 64,  l + 64);
                async_se4(g + 128, l + 128);
            }
        }
        // gate GEMMs (prefetch resolves underneath)
        float4v mv[2][5];
        #pragma unroll
        for (int g = 0; g < 5; ++g) {
            const int n = g * 128 + fc2 * 64 + wv * 16 + l16;
            float4v p1a = zero4, p1b = zero4, p2a = zero4, p2b = zero4;
            #pragma unroll
            for (int kk = 0; kk < 4; ++kk) {
                const int k = kk * 32 + quad * 8;
                short8 b1f = *(const short8*)&Wt2[n * 128 + k];
                short8 b2f = *(const short8*)&Wtw2[n * 128 + k];
                p1a = __builtin_amdgcn_mfma_f32_16x16x32_bf16(ha[0][kk], b1f, p1a, 0, 0, 0);
                p1b = __builtin_amdgcn_mfma_f32_16x16x32_bf16(ha[1][kk], b1f, p1b, 0, 0, 0);
                p2a = __builtin_amdgcn_mfma_f32_16x16x32_bf16(hb[0][kk], b2f, p2a, 0, 0, 0);
                p2b = __builtin_amdgcn_mfma_f32_16x16x32_bf16(hb[1][kk], b2f, p2b, 0, 0, 0);
            }
            const float b2v  = phi_b2[n];
            const float bw2v = w_b2[n];
            mv[0][g] = (p1a + b2v) * (p2a + bw2v);
            mv[1][g] = (p1b + b2v) * (p2b + bw2v);
        }
        // drain own prefetches, then sync so all waves' rows are visible.
        asm volatile("s_waitcnt vmcnt(0)" ::: "memory");
        __builtin_amdgcn_sched_barrier(0);
        lds_barrier();
        // epilogue: se from LDS, dq direct; v overwrites se in place
        {
            const int fl = wv * 16 + l16;        // 0..63 within chunk
            const int fg = fc2 * 64 + fl;
            #pragma unroll
            for (int rt = 0; rt < 2; ++rt) {
                #pragma unroll
                for (int r = 0; r < 4; ++r) {
                    const int row = rt * 16 + quad * 4 + r;
                    const float gate = mv[rt][0][r];
                    const float cpg  = mv[rt][1][r];
                    const float sc   = mv[rt][2][r];
                    const float dsv  = mv[rt][3][r];
                    const float dev  = mv[rt][4][r];
                    const int dn = s_dst[row], e = s_e[row];
                    const float ex = s_dir[row][0], ey = s_dir[row][1], ez = s_dir[row][2];
                    float* pp = PH2 + row * PH2_STRIDE;
                    const float sx = pp[fl * 3 + 0];
                    const float sy = pp[fl * 3 + 1];
                    const float sz = pp[fl * 3 + 2];
                    const float* dq = eqf + ((size_t)dn * 128 + fg) * 3;
                    const float dx = dq[0], dy = dq[1], dz = dq[2];
                    const float cx = ey * dz - ez * dy;
                    const float cy = ez * dx - ex * dz;
                    const float cz = ex * dy - ey * dx;
                    pp[fl * 3 + 0] = sc * ex + gate * sx + cpg * cx;
                    pp[fl * 3 + 1] = sc * ey + gate * sy + cpg * cy;
                    pp[fl * 3 + 2] = sc * ez + gate * sz + cpg * cz;
                    pp[192 + fl]   = dsv;
                    edge_out[(size_t)e * 128 + fg] = bf2f(a1bv[fc2][rt * 4 + r]) + dev;
                }
            }
        }
        lds_barrier();
        // segmented reduction over ALL 32 sorted-dst rows (~1 atomic per run)
        {
            const int fgr = fc2 * 64 + red_f;
            float acc = 0.f;
            int prev = s_dst[0];
            #pragma unroll
            for (int r = 0; r < 32; ++r) {
                const int d = s_dst[r];
                const float v = PH2[r * PH2_STRIDE + red_fo];
                if (d != prev) {
                    if (red_c < 3) atomicAdd(eq_out + ((size_t)prev * 128 + fgr) * 3 + red_c, acc);
                    else           atomicAdd(inv_out + (size_t)prev * 128 + fgr, acc);
                    acc = 0.f; prev = d;
                }
                acc += v;
            }
            if (red_c < 3) atomicAdd(eq_out + ((size_t)prev * 128 + fgr) * 3 + red_c, acc);
            else           atomicAdd(inv_out + (size_t)prev * 128 + fgr, acc);
        }
        lds_barrier();
    }
}

extern "C" void kernel_launch(void* const* d_in, const int* in_sizes, int n_in,
                              void* d_out, int out_size, void* d_ws, size_t ws_size,
                              hipStream_t stream) {
    const int*   eidx     = (const int*)d_in[0];
    const float* node_inv = (const float*)d_in[1];
    const float* eqf      = (const float*)d_in[2];
    const float* edge_inv = (const float*)d_in[3];
    const float* dist     = (const float*)d_in[4];
    const float* dir      = (const float*)d_in[5];
    const float* phi_W1   = (const float*)d_in[6];
    const float* phi_b1   = (const float*)d_in[7];
    const float* phi_W2   = (const float*)d_in[8];
    const float* phi_b2   = (const float*)d_in[9];
    const float* w_W1     = (const float*)d_in[10];
    const float* w_b1     = (const float*)d_in[11];
    const float* w_W2     = (const float*)d_in[12];
    const float* w_b2     = (const float*)d_in[13];
    float* out = (float*)d_out;
    unsigned short* wsW = (unsigned short*)d_ws;
    int* counts = (int*)((char*)d_ws + CNT_BYTE);
    int* cursor = (int*)((char*)d_ws + CUR_BYTE);
    int* perm   = (int*)((char*)d_ws + PERM_BYTE);

    prep_fused<<<(EQ_OUT_SZ + INV_OUT_SZ) / 4 / 256, 256, 0, stream>>>(
        phi_W1, w_W1, phi_W2, w_W2, wsW, counts, eqf, node_inv, out);
    hist_kernel<<<(E_EDGES + 255) / 256, 256, 0, stream>>>(eidx, counts);
    scan_kernel<<<1, 1024, 0, stream>>>(counts, cursor);
    scatter_kernel<<<(E_EDGES + 255) / 256, 256, 0, stream>>>(eidx, cursor, perm);
    edge_kernel<<<E_EDGES / 32, 256, 0, stream>>>(eidx, node_inv, eqf, edge_inv, dist, dir,
                                                  phi_b1, phi_b2, w_b1, w_b2, wsW, perm, out);
}